// Round 13
// baseline (1314.020 us; speedup 1.0000x reference)
//
#include <hip/hip_runtime.h>
#include <hip/hip_bf16.h>
#include <cstdint>

#define D  512
#define D2 1024
#define BB 128
#define SS 128
#define NN 196
#define TT 12

typedef unsigned short u16;
typedef __attribute__((ext_vector_type(8))) short short8v;
typedef __attribute__((ext_vector_type(4))) float f32x4;

__device__ __forceinline__ float bf2f(u16 h){
  union { unsigned int u; float f; } v; v.u = ((unsigned int)h) << 16; return v.f;
}

__device__ __forceinline__ float LDX(const void* p, size_t i, int isbf){
  if (isbf) return bf2f(((const u16*)p)[i]);
  return ((const float*)p)[i];
}

__device__ __forceinline__ float4 LD4(const void* p, size_t i, int isbf){
  if (isbf){
    ushort4 w = *(const ushort4*)((const u16*)p + i);
    return make_float4(bf2f(w.x), bf2f(w.y), bf2f(w.z), bf2f(w.w));
  }
  return *(const float4*)((const float*)p + i);
}

// split fp32 into bf16 hi (truncation) + bf16 lo (truncated residual).
__device__ __forceinline__ void bfsplit(float x, short &h, short &l){
  unsigned u = __float_as_uint(x);
  unsigned hu = u & 0xFFFF0000u;
  float r = x - __uint_as_float(hu);
  h = (short)(u >> 16);
  l = (short)(__float_as_uint(r) >> 16);
}

// ---------------- detect input dtype ----------------
__global__ __launch_bounds__(256) void k_detect(const u16* ctx, int* flag){
  __shared__ int cnt;
  if (threadIdx.x == 0) cnt = 0;
  __syncthreads();
  int bad = 0;
  for (int i = threadIdx.x; i < 8192; i += 256){
    int e = (ctx[i] >> 7) & 0xFF;
    if (e == 0xFF || (e != 0 && (e < 90 || e > 160))) bad++;
  }
  atomicAdd(&cnt, bad);
  __syncthreads();
  if (threadIdx.x == 0) *flag = (cnt > 100) ? 0 : 1;   // 1 = bf16, 0 = fp32
}

// ---------------- prep1: weight transposes + P/pp2 presets + initA (+mmc) ----------------
__global__ __launch_bounds__(256) void k_prep1(const void* Wcq, const void* Wca,
      const void* Wwc, const void* Wrm, const void* Wrc, const void* Wra,
      const void* bp, const void* bcq, const void* ctrl0, const void* mem0, const void* brm,
      const void* bwc,
      float* W1f, float* Wwcf, float* WrmTf, float* W2f,
      float* P, float* pp2, float* ubase, float* mmb, float* mmc, const int* flag){
  const int isbf = *flag;
  __shared__ float lds[32][33];
  int bk = blockIdx.x, tid = threadIdx.x;
  int tx = tid & 31, ty = tid >> 5;
  if (bk >= 1216){                       // initA: 48 blocks (ubase / mmb / mmc)
    int ib = bk - 1216;
    int lane = tid & 63, w = tid >> 6;
    int grp = lane >> 3, k = lane & 7;
    int kind = ib >> 4;                  // 0=ubase, 1=mmb(mem0), 2=mmc(bwc)
    int o = (ib & 15)*32 + w*8 + grp;
    const void* vec = (kind == 0) ? ctrl0 : ((kind == 1) ? mem0 : bwc);
    const void* mat = (kind == 0) ? Wcq : Wrm;
    int ld = (kind == 0) ? D2 : D;
    float acc = 0.f;
    #pragma unroll 4
    for (int it = 0; it < 16; it++){
      int d = it*32 + k*4;
      float4 v = LD4(vec, d, isbf);
      float4 m = LD4(mat, (size_t)o*ld + d, isbf);
      acc += v.x*m.x + v.y*m.y + v.z*m.z + v.w*m.w;
    }
    acc += __shfl_xor(acc, 1, 64);
    acc += __shfl_xor(acc, 2, 64);
    acc += __shfl_xor(acc, 4, 64);
    if (k == 0){
      if (kind == 0)      ubase[o] = acc * LDX(Wca, o, isbf);
      else if (kind == 1) mmb[o]   = acc + LDX(brm, o, isbf);
      else                mmc[o]   = acc + LDX(brm, o, isbf);
    }
    return;
  }
  if (bk >= 1152){                       // pp2 preset = bcq[j]*Wca[j] : 64 blocks
    int l = bk - 1152;
    for (int idx = l*256 + tid; idx < 786432; idx += 64*256){
      int j = (idx >> 7) & 511;
      pp2[idx] = LDX(bcq, j, isbf) * LDX(Wca, j, isbf);
    }
    return;
  }
  if (bk >= 1088){                       // P preset = bp : 64 blocks
    int l = bk - 1088;
    for (int idx = l*256 + tid; idx < 786432; idx += 64*256)
      P[idx] = LDX(bp, idx >> 7, isbf);
    return;
  }
  if (bk >= 1024){                       // W2f = Wrc * Wra : 64 blocks
    int l = bk - 1024;
    if (isbf){
      const u16* w = (const u16*)Wrc; const u16* s = (const u16*)Wra;
      for (int idx = l*256 + tid; idx < 524288; idx += 64*256)
        W2f[idx] = bf2f(w[idx]) * bf2f(s[idx >> 10]);
    } else {
      const float* w = (const float*)Wrc; const float* s = (const float*)Wra;
      for (int idx = l*256 + tid; idx < 524288; idx += 64*256)
        W2f[idx] = w[idx] * s[idx >> 10];
    }
    return;
  }
  const void* in = nullptr; const void* scale = nullptr; float* out = nullptr;
  int ld = 0, R = 0, tR = 0, tC = 0;
  if (bk < 256)      { int l = bk;       in = Wcq; ld = 1024; R = 512; out = W1f;  scale = Wca; tR = l & 15; tC = l >> 4; }
  else if (bk < 768) { int l = bk - 256; in = Wwc; ld = 1024; R = 512; out = Wwcf; tR = l & 15; tC = l >> 4; }
  else               { int l = bk - 768; in = Wrm; ld = 512;  R = 512; out = WrmTf;tR = l & 15; tC = l >> 4; }
  int r0 = tR*32, c0 = tC*32;
  #pragma unroll
  for (int kk = 0; kk < 4; kk++){
    int r = r0 + ty + kk*8;
    float v = LDX(in, (size_t)r*ld + c0 + tx, isbf);
    if (scale) v *= LDX(scale, r, isbf);
    lds[tx][ty + kk*8] = v;
  }
  __syncthreads();
  #pragma unroll
  for (int kk = 0; kk < 4; kk++){
    int oc = ty + kk*8;
    out[(size_t)(c0 + oc)*R + r0 + tx] = lds[oc][tx];
  }
}

// ---------------- k_gf: GF[o][i] = sum_j Wwcf[o][j] * WrmTf[j][i]  (= (Wrm@Wwc)[i][o]) -----
// (verified in rounds 7/8: mm = mmc + GF^T-gemv over [r; m_prev] matches reference)
__global__ __launch_bounds__(256) void k_gf(const float* Wwcf, const float* WrmTf, float* GF){
  __shared__ float wr[4][512];
  int o0 = blockIdx.x * 4, tid = threadIdx.x;    // 256 blocks
  for (int idx = tid; idx < 4*512; idx += 256)
    wr[idx >> 9][idx & 511] = Wwcf[(size_t)(o0 + (idx >> 9))*D + (idx & 511)];
  __syncthreads();
  float a0[4] = {0.f,0.f,0.f,0.f}, a1[4] = {0.f,0.f,0.f,0.f};
  for (int j = 0; j < 512; j++){
    float x = WrmTf[(size_t)j*D + tid];
    float y = WrmTf[(size_t)j*D + 256 + tid];
    #pragma unroll
    for (int r = 0; r < 4; r++){ a0[r] += wr[r][j]*x; a1[r] += wr[r][j]*y; }
  }
  #pragma unroll
  for (int r = 0; r < 4; r++){
    GF[(size_t)(o0 + r)*D + tid]       = a0[r];
    GF[(size_t)(o0 + r)*D + 256 + tid] = a1[r];
  }
}

// ---------------- k_pack: [bk<128] q->QF hi/lo bf16 ; [bk>=128] kmat -> kT (wide transpose) --
__global__ __launch_bounds__(256) void k_pack(const void* q, u16* QF,
                                              const void* kmat, float* kT, const int* flag){
  const int isbf = *flag;
  __shared__ float lds[64][201];
  int bk = blockIdx.x, tid = threadIdx.x;
  if (bk < 128){
    u16* QH = QF;
    u16* QL = QF + 131072;
    for (int idx = bk*256 + tid; idx < 131072; idx += 128*256){
      int b = idx >> 10, x = idx & 1023;
      int o = ((x >> 3) << 10) + (b << 3) + (x & 7);
      if (isbf){
        QH[o] = ((const u16*)q)[idx];
        QL[o] = 0;
      } else {
        short h, l;
        bfsplit(((const float*)q)[idx], h, l);
        QH[o] = (u16)h;
        QL[o] = (u16)l;
      }
    }
    return;
  }
  int l = bk - 128;                 // 1024 = 128 b x 8 d-tiles(64)
  int b = l >> 3, dt = l & 7;
  int d0 = dt*64;
  int r = tid >> 2, q4 = tid & 3;
  const size_t rowbase = ((size_t)b*D + d0 + r)*NN;
  #pragma unroll
  for (int p = 0; p < 13; p++){
    int j = q4 + p*4;
    if (j < 49){
      float4 v = LD4(kmat, rowbase + 4*j, isbf);
      *(float4*)&lds[r][4*j] = v;
    }
  }
  __syncthreads();
  int n_loc = tid >> 4, f = tid & 15;
  #pragma unroll
  for (int p = 0; p < 13; p++){
    int n = p*16 + n_loc;
    if (n < NN){
      float4 v = make_float4(lds[4*f][n], lds[4*f+1][n], lds[4*f+2][n], lds[4*f+3][n]);
      *(float4*)&kT[((size_t)b*NN + n)*D + d0 + 4*f] = v;
    }
  }
}

// ---------------- k_Pmfma: P += Wp @ qT via 16x16x32 bf16 MFMA (split hi/lo) ----------------
__global__ __launch_bounds__(256) void k_Pmfma(const void* Wp, const u16* QF,
                                               float* P, const int* flag){
  const int isbf = *flag;
  const u16* QH = QF;
  const u16* QL = QF + 131072;
  int bk = blockIdx.x;
  int mt = bk >> 2, kc = bk & 3;
  int m0 = mt * 32;
  int tid = threadIdx.x;
  int ln = tid & 63, w = tid >> 6;
  int msub = w >> 1, nh = w & 1;
  int row  = m0 + msub*16 + (ln & 15);   // A row (0..6143)
  int koff = ln >> 4;                    // 0..3 : k-subgroup of 8
  f32x4 acc[4];
  #pragma unroll
  for (int i = 0; i < 4; i++) acc[i] = (f32x4){0.f, 0.f, 0.f, 0.f};

  for (int ks = 0; ks < 8; ks++){
    int k0 = kc*256 + ks*32;
    short8v ah, al;
    if (isbf){
      const u16* wr = (const u16*)Wp + (size_t)row*D2 + k0 + koff*8;
      ah = *(const short8v*)wr;
    } else {
      const float* wr = (const float*)Wp + (size_t)row*D2 + k0 + koff*8;
      float4 f0 = *(const float4*)wr;
      float4 f1 = *(const float4*)(wr + 4);
      float fs[8] = {f0.x, f0.y, f0.z, f0.w, f1.x, f1.y, f1.z, f1.w};
      #pragma unroll
      for (int j = 0; j < 8; j++){
        short h, l;
        bfsplit(fs[j], h, l);
        ah[j] = h; al[j] = l;
      }
    }
    int qrow = ((k0 >> 3) + koff) << 10;   // *1024
    #pragma unroll
    for (int nt = 0; nt < 4; nt++){
      int col = (nh*4 + nt)*16 + (ln & 15);
      short8v bh = *(const short8v*)(QH + qrow + (col << 3));
      acc[nt] = __builtin_amdgcn_mfma_f32_16x16x32_bf16(ah, bh, acc[nt], 0, 0, 0);
      if (!isbf){
        short8v bl = *(const short8v*)(QL + qrow + (col << 3));
        acc[nt] = __builtin_amdgcn_mfma_f32_16x16x32_bf16(ah, bl, acc[nt], 0, 0, 0);
        acc[nt] = __builtin_amdgcn_mfma_f32_16x16x32_bf16(al, bh, acc[nt], 0, 0, 0);
      }
    }
  }
  // C/D layout (m89-verified): col = lane&15, row = (lane>>4)*4 + reg
  int orow = m0 + msub*16 + (ln >> 4)*4;
  #pragma unroll
  for (int nt = 0; nt < 4; nt++){
    int b = (nh*4 + nt)*16 + (ln & 15);
    #pragma unroll
    for (int r = 0; r < 4; r++)
      atomicAdd(&P[(size_t)(orow + r)*BB + b], acc[nt][r]);
  }
}

// ---------------- K_pp2: K-split x2, atomic into (bcq*Wca)-preset pp2 ----------------
__global__ __launch_bounds__(512) void k_pp2(const float* P, const void* Wcq,
                                             const void* Wca, float* pp2, const int* flag){
  const int isbf = *flag;
  int bk = blockIdx.x;                      // 768 = 12t * 32jt * 2kc
  int t = bk >> 6; int r = bk & 63; int jt = r >> 1; int kc = r & 1;
  int tid = threadIdx.x;
  int b = tid & 127;
  int ih = __builtin_amdgcn_readfirstlane(tid >> 7);
  int j0 = jt*16 + ih*4;
  float acc[4] = {0.f, 0.f, 0.f, 0.f};
  int e0k = kc*256;
  if (isbf){
    const u16* w = (const u16*)Wcq;
    for (int e = e0k; e < e0k + 256; e += 8){
      float a[8];
      #pragma unroll
      for (int u = 0; u < 8; u++) a[u] = P[(size_t)(t*D + e + u)*BB + b];
      #pragma unroll
      for (int kk = 0; kk < 4; kk++){
        ushort4 w0 = *(const ushort4*)(w + (size_t)(j0+kk)*D2 + D + e);
        ushort4 w1 = *(const ushort4*)(w + (size_t)(j0+kk)*D2 + D + e + 4);
        acc[kk] += a[0]*bf2f(w0.x) + a[1]*bf2f(w0.y) + a[2]*bf2f(w0.z) + a[3]*bf2f(w0.w)
                 + a[4]*bf2f(w1.x) + a[5]*bf2f(w1.y) + a[6]*bf2f(w1.z) + a[7]*bf2f(w1.w);
      }
    }
  } else {
    const float* w = (const float*)Wcq;
    for (int e = e0k; e < e0k + 256; e += 8){
      float a[8];
      #pragma unroll
      for (int u = 0; u < 8; u++) a[u] = P[(size_t)(t*D + e + u)*BB + b];
      #pragma unroll
      for (int kk = 0; kk < 4; kk++){
        float4 w0 = *(const float4*)(w + (size_t)(j0+kk)*D2 + D + e);
        float4 w1 = *(const float4*)(w + (size_t)(j0+kk)*D2 + D + e + 4);
        acc[kk] += a[0]*w0.x + a[1]*w0.y + a[2]*w0.z + a[3]*w0.w
                 + a[4]*w1.x + a[5]*w1.y + a[6]*w1.z + a[7]*w1.w;
      }
    }
  }
  #pragma unroll
  for (int kk = 0; kk < 4; kk++)
    atomicAdd(&pp2[(size_t)(t*D + j0 + kk)*BB + b], acc[kk] * LDX(Wca, j0 + kk, isbf));
}

// ---------------- K_initB: u0 and m_{-1} ----------------
__global__ __launch_bounds__(256) void k_initB(const float* ubase, const void* mem0,
                                               const float* pp2,
                                               float* u0, float* act0, const int* flag){
  const int isbf = *flag;
  for (int idx = blockIdx.x*256 + threadIdx.x; idx < 2*D*BB; idx += 64*256){
    if (idx < D*BB) u0[idx] = ubase[idx >> 7] + pp2[idx];
    else          { int x = idx - D*BB; act0[D*BB + x] = LDX(mem0, x >> 7, isbf); }
  }
}

// ================ KA: [k-finish -> r_{t-1}] + [full ctx-attn -> cbuf] + presets ============
// bk <  512 : (b, qc) k-finish: pbuf partials -> softmax -> kT weighted sum   (t>0)
// bk < 1024 : (b, qc) ctx-attn: ALL 128 logits + softmax + qc-chunk wsum     (t<TT)
// bk < 1056 : u_nxt preset = pp2_next                                         (t<TT-1)
// bk < 1088 : bwc preset into act_cur rows D..2D                              (t>0; incl t=TT epilogue)
__global__ __launch_bounds__(512) void k_KA(const void* ctx, const float* u_cur,
                                            const float* pbuf, const float* kT,
                                            float* r_out, float* cbuf,
                                            float* u_nxt, const float* pp2_next,
                                            float* act_cur, const void* bwc,
                                            int t, const int* flag){
  __shared__ float sm[1280];
  int bk = blockIdx.x, tid = threadIdx.x;
  const int isbf = *flag;
  if (bk < 512){
    if (t == 0) return;
    float* lg   = sm;            // 256
    float* red  = sm + 256;      // 256
    float* psum = sm + 512;      // 512
    int b = bk & 127, qc = bk >> 7;
    if (tid < 256){
      float s;
      if (tid < NN){
        s = 0.f;
        #pragma unroll
        for (int c = 0; c < 8; c++)
          s += pbuf[((size_t)c*BB + b)*256 + tid];
      } else s = -INFINITY;
      lg[tid] = s; red[tid] = s;
    }
    __syncthreads();
    for (int off = 128; off; off >>= 1){ if (tid < off) red[tid] = fmaxf(red[tid], red[tid+off]); __syncthreads(); }
    float M = red[0];
    __syncthreads();
    if (tid < 256){ float e = (tid < NN) ? __expf(lg[tid] - M) : 0.f; lg[tid] = e; red[tid] = e; }
    __syncthreads();
    for (int off = 128; off; off >>= 1){ if (tid < off) red[tid] += red[tid+off]; __syncthreads(); }
    float inv = 1.f / red[0];
    int ng = tid >> 7, dl = tid & 127;     // 4 n-groups x 128 d-lanes
    const float* kTb = kT + ((size_t)b*NN + ng*49)*D + qc*128 + dl;
    float acc = 0.f;
    for (int j = 0; j < 49; j++)
      acc += lg[ng*49 + j] * kTb[(size_t)j*D];
    psum[ng*128 + dl] = acc;
    __syncthreads();
    if (tid < 128)
      r_out[(size_t)(qc*128 + tid)*BB + b] =
        (psum[tid] + psum[128 + tid] + psum[256 + tid] + psum[384 + tid]) * inv;
    return;
  }
  if (bk < 1024){
    // ---- full ctx attention for (b, qc) ----
    if (t >= TT) return;
    int l = bk - 512;
    int b = l & 127, qc = l >> 7;
    float* us   = sm;            // 512
    float* lg   = sm + 512;      // 128
    float* red  = sm + 640;      // 128
    float* psum = sm + 768;      // 512
    us[tid] = u_cur[(size_t)tid*BB + b];
    __syncthreads();
    int lane = tid & 63, wv = tid >> 6;
    float ur[8];
    #pragma unroll
    for (int j = 0; j < 8; j++) ur[j] = us[lane*8 + j];
    for (int rr = 0; rr < 16; rr++){
      int s = wv*16 + rr;
      size_t base = ((size_t)(b*SS + s))*D + lane*8;
      float4 c0 = LD4(ctx, base, isbf);
      float4 c1 = LD4(ctx, base + 4, isbf);
      float dot = ur[0]*c0.x + ur[1]*c0.y + ur[2]*c0.z + ur[3]*c0.w
                + ur[4]*c1.x + ur[5]*c1.y + ur[6]*c1.z + ur[7]*c1.w;
      #pragma unroll
      for (int off = 32; off; off >>= 1) dot += __shfl_down(dot, off, 64);
      if (lane == 0) lg[s] = dot;
    }
    __syncthreads();
    if (tid < 128) red[tid] = lg[tid];
    __syncthreads();
    for (int off = 64; off; off >>= 1){ if (tid < off) red[tid] = fmaxf(red[tid], red[tid+off]); __syncthreads(); }
    float M = red[0];
    __syncthreads();
    if (tid < 128){ float e = __expf(lg[tid] - M); lg[tid] = e; red[tid] = e; }
    __syncthreads();
    for (int off = 64; off; off >>= 1){ if (tid < off) red[tid] += red[tid+off]; __syncthreads(); }
    float inv = 1.f / red[0];
    int sg = tid >> 7, dl = tid & 127;     // 4 s-groups x 128 d-lanes
    int d = qc*128 + dl;
    float acc = 0.f;
    for (int j = 0; j < 32; j++){
      int s = sg*32 + j;
      acc += lg[s] * LDX(ctx, ((size_t)(b*SS + s))*D + d, isbf);
    }
    psum[sg*128 + dl] = acc;
    __syncthreads();
    if (tid < 128)
      cbuf[(size_t)(qc*128 + tid)*BB + b] =
        (psum[tid] + psum[128 + tid] + psum[256 + tid] + psum[384 + tid]) * inv;
    return;
  }
  if (bk < 1056){
    if (t >= TT-1) return;
    int l = bk - 1024;
    for (int x = l*512 + tid; x < D*BB; x += 32*512) u_nxt[x] = pp2_next[x];
  } else {
    // bwc preset into act_cur rows D..2D — KC's m-gemv atomics land on this.
    // t>0 only (at t=0 act_cur D..2D holds mem0, consumed at t=1). Runs at t=TT (epilogue).
    if (t == 0) return;
    int l = bk - 1056;
    for (int x = l*512 + tid; x < D*BB; x += 32*512)
      act_cur[D*BB + x] = LDX(bwc, x >> 7, isbf);
  }
}

// ================ KC: [fused w/mm(GF)/u2 + logit partials] + [m-gemv] + [u-gemv] ===========
// bk <  512 : (b, ch2) fused: w (W2f), mm = mmc + GF^T·act_prev (t==0 -> mmb), u2,
//             kmat logit partials -> pbuf
// bk < 1024 : m-gemv: act_cur rows D..2D += Wwcf^T · act_prev (bwc preset by KA; t>0)
// bk < 1280 : u-gemv: u_nxt += W1f^T · cbuf (t<TT-1)
__global__ __launch_bounds__(512) void k_KC(const void* kmat, const float* cbuf,
                                            const float* act_prev, const float* W2f,
                                            const float* GF, const float* mmc,
                                            const float* mmb, const float* Wwcf,
                                            float* act_cur, float* pbuf,
                                            const float* W1f, float* u_nxt,
                                            int t, const int* flag){
  __shared__ float cb[512];
  __shared__ float ap[1024];
  __shared__ float wv2[256];
  __shared__ float mmv[128];
  __shared__ float u2[128];
  int bk = blockIdx.x, tid = threadIdx.x;
  const int isbf = *flag;
  if (bk < 512){
    int b = bk & 127, ch2 = bk >> 7;      // ch2: 0..3
    int d0 = ch2*128;
    cb[tid] = cbuf[(size_t)tid*BB + b];
    if (t > 0){
      ap[tid]       = act_prev[(size_t)tid*BB + b];
      ap[512 + tid] = act_prev[(size_t)(512 + tid)*BB + b];
    }
    __syncthreads();
    if (tid < 256){
      int e = (tid < 128) ? (d0 + tid) : (D + d0 + (tid - 128));
      float c0=0.f,c1=0.f,c2=0.f,c3=0.f,c4=0.f,c5=0.f,c6=0.f,c7=0.f;
      for (int j = 0; j < 512; j += 8){
        c0 += cb[j  ]*W2f[(size_t)(j  )*D2 + e];
        c1 += cb[j+1]*W2f[(size_t)(j+1)*D2 + e];
        c2 += cb[j+2]*W2f[(size_t)(j+2)*D2 + e];
        c3 += cb[j+3]*W2f[(size_t)(j+3)*D2 + e];
        c4 += cb[j+4]*W2f[(size_t)(j+4)*D2 + e];
        c5 += cb[j+5]*W2f[(size_t)(j+5)*D2 + e];
        c6 += cb[j+6]*W2f[(size_t)(j+6)*D2 + e];
        c7 += cb[j+7]*W2f[(size_t)(j+7)*D2 + e];
      }
      wv2[tid] = (((c0+c1)+(c2+c3)) + ((c4+c5)+(c6+c7)));
    } else if (tid < 384){
      int tm = tid - 256;
      int d = d0 + tm;
      if (t == 0){
        mmv[tm] = mmb[d];
      } else {
        float c0=0.f,c1=0.f,c2=0.f,c3=0.f,c4=0.f,c5=0.f,c6=0.f,c7=0.f;
        for (int j = 0; j < 1024; j += 8){
          c0 += ap[j  ]*GF[(size_t)(j  )*D + d];
          c1 += ap[j+1]*GF[(size_t)(j+1)*D + d];
          c2 += ap[j+2]*GF[(size_t)(j+2)*D + d];
          c3 += ap[j+3]*GF[(size_t)(j+3)*D + d];
          c4 += ap[j+4]*GF[(size_t)(j+4)*D + d];
          c5 += ap[j+5]*GF[(size_t)(j+5)*D + d];
          c6 += ap[j+6]*GF[(size_t)(j+6)*D + d];
          c7 += ap[j+7]*GF[(size_t)(j+7)*D + d];
        }
        mmv[tm] = mmc[d] + (((c0+c1)+(c2+c3)) + ((c4+c5)+(c6+c7)));
      }
    }
    __syncthreads();
    if (tid < 128) u2[tid] = wv2[tid]*mmv[tid] + wv2[128 + tid];
    __syncthreads();
    int half = tid >> 8;                  // 0..1 -> 64-d sub-chunk
    int n = tid & 255;
    int dd0 = half*64;
    float part = 0.f;
    if (n < NN){
      float c[8];
      #pragma unroll
      for (int u = 0; u < 8; u++) c[u] = 0.f;
      if (isbf){
        const u16* kb = (const u16*)kmat + (size_t)b*D*NN + (size_t)(d0+dd0)*NN + n;
        for (int dd = 0; dd < 64; dd += 8){
          #pragma unroll
          for (int u = 0; u < 8; u++) c[u] += u2[dd0+dd+u]*bf2f(kb[(size_t)(dd+u)*NN]);
        }
      } else {
        const float* kb = (const float*)kmat + (size_t)b*D*NN + (size_t)(d0+dd0)*NN + n;
        for (int dd = 0; dd < 64; dd += 8){
          #pragma unroll
          for (int u = 0; u < 8; u++) c[u] += u2[dd0+dd+u]*kb[(size_t)(dd+u)*NN];
        }
      }
      part = (((c[0]+c[1]) + (c[2]+c[3])) + ((c[4]+c[5]) + (c[6]+c[7])));
    }
    int chunk = ch2*2 + half;             // 0..7
    pbuf[((size_t)chunk*BB + b)*256 + n] = part;
    return;
  }
  int b = tid & 127;
  int ih = __builtin_amdgcn_readfirstlane(tid >> 7);   // 0..3
  if (bk < 1024){
    if (t == 0) return;
    int l = bk - 512;                    // 0..511
    int it = l >> 3, kc = l & 7;
    int ih0 = ih & 1, ih1 = ih >> 1;
    int i0 = it*8 + ih0*4;
    int e0 = kc*128 + ih1*64;
    float acc[4] = {0.f,0.f,0.f,0.f};
    for (int e = e0; e < e0 + 64; e += 8){
      float av[8];
      #pragma unroll
      for (int u = 0; u < 8; u++) av[u] = act_prev[(size_t)(e+u)*BB + b];
      #pragma unroll
      for (int u = 0; u < 8; u++){
        float4 w0 = *(const float4*)(Wwcf + (size_t)(e+u)*D + i0);
        acc[0]+=av[u]*w0.x; acc[1]+=av[u]*w0.y; acc[2]+=av[u]*w0.z; acc[3]+=av[u]*w0.w;
      }
    }
    #pragma unroll
    for (int kk = 0; kk < 4; kk++)
      atomicAdd(&act_cur[(size_t)(D + i0 + kk)*BB + b], acc[kk]);
  } else {
    if (t >= TT-1) return;
    int l = bk - 1024;                   // 0..255
    int jt = l >> 1, kc = l & 1;
    int j = jt*4 + ih;
    float c0 = 0.f, c1 = 0.f, c2 = 0.f, c3 = 0.f, c4 = 0.f, c5 = 0.f, c6 = 0.f, c7 = 0.f;
    int e0 = kc*256;
    for (int e = e0; e < e0 + 256; e += 8){
      c0 += cbuf[(e  )*BB + b] * W1f[(size_t)(e  )*D + j];
      c1 += cbuf[(e+1)*BB + b] * W1f[(size_t)(e+1)*D + j];
      c2 += cbuf[(e+2)*BB + b] * W1f[(size_t)(e+2)*D + j];
      c3 += cbuf[(e+3)*BB + b] * W1f[(size_t)(e+3)*D + j];
      c4 += cbuf[(e+4)*BB + b] * W1f[(size_t)(e+4)*D + j];
      c5 += cbuf[(e+5)*BB + b] * W1f[(size_t)(e+5)*D + j];
      c6 += cbuf[(e+6)*BB + b] * W1f[(size_t)(e+6)*D + j];
      c7 += cbuf[(e+7)*BB + b] * W1f[(size_t)(e+7)*D + j];
    }
    float acc = (((c0+c1)+(c2+c3)) + ((c4+c5)+(c6+c7)));
    atomicAdd(&u_nxt[(size_t)j*BB + b], acc);
  }
}

// ================ k_moutA: m_T = bwc + Wwc^T [r_T; m_{T-1}] (K-split x16) ================
__global__ __launch_bounds__(512) void k_moutA(const float* act_fin, const float* Wwcf,
                                               float* act_out){
  int bk = blockIdx.x, tid = threadIdx.x;   // 512 blocks
  int b = tid & 127;
  int ih = __builtin_amdgcn_readfirstlane(tid >> 7);
  int it = bk >> 3, kc = bk & 7;
  int ih0 = ih & 1, ih1 = ih >> 1;
  int i0 = it*8 + ih0*4;
  int e0 = kc*128 + ih1*64;
  float acc[4] = {0.f,0.f,0.f,0.f};
  for (int e = e0; e < e0 + 64; e += 8){
    float av[8];
    #pragma unroll
    for (int u = 0; u < 8; u++) av[u] = act_fin[(size_t)(e+u)*BB + b];
    #pragma unroll
    for (int u = 0; u < 8; u++){
      float4 w0 = *(const float4*)(Wwcf + (size_t)(e+u)*D + i0);
      acc[0]+=av[u]*w0.x; acc[1]+=av[u]*w0.y; acc[2]+=av[u]*w0.z; acc[3]+=av[u]*w0.w;
    }
  }
  #pragma unroll
  for (int kk = 0; kk < 4; kk++)
    atomicAdd(&act_out[(size_t)(D + i0 + kk)*BB + b], acc[kk]);
}

// ================ k_outT: m[i,b] fp32 -> out[b,i] (bf16 or f32) ================
__global__ __launch_bounds__(256) void k_outT(const float* act_fin, void* out, const int* flag){
  const int isbf = *flag;
  __shared__ float lds[32][33];
  int bk = blockIdx.x;
  int it = bk >> 2, bt = bk & 3;
  int tx = threadIdx.x & 31, ty = threadIdx.x >> 5;
  #pragma unroll
  for (int kk = 0; kk < 4; kk++){
    int i = it*32 + ty + kk*8;
    lds[tx][ty + kk*8] = act_fin[(size_t)(D + i)*BB + bt*32 + tx];
  }
  __syncthreads();
  if (isbf){
    __hip_bfloat16* o = (__hip_bfloat16*)out;
    #pragma unroll
    for (int kk = 0; kk < 4; kk++){
      int bb = bt*32 + ty + kk*8;
      o[(size_t)bb*D + it*32 + tx] = __float2bfloat16(lds[ty + kk*8][tx]);
    }
  } else {
    float* o = (float*)out;
    #pragma unroll
    for (int kk = 0; kk < 4; kk++){
      int bb = bt*32 + ty + kk*8;
      o[(size_t)bb*D + it*32 + tx] = lds[ty + kk*8][tx];
    }
  }
}

extern "C" void kernel_launch(void* const* d_in, const int* in_sizes, int n_in,
                              void* d_out, int out_size, void* d_ws, size_t ws_size,
                              hipStream_t stream){
  const void* ctx  = d_in[0];
  const void* q    = d_in[1];
  const void* kmat = d_in[2];
  const void* mem0 = d_in[3];
  const void* ctrl0= d_in[4];
  const void* Wp   = d_in[5];
  const void* bp   = d_in[6];
  const void* Wcq  = d_in[7];
  const void* bcq  = d_in[8];
  const void* Wca  = d_in[9];
  const void* Wrm  = d_in[11];
  const void* brm  = d_in[12];
  const void* Wrc  = d_in[13];
  const void* Wra  = d_in[15];
  const void* Wwc  = d_in[17];
  const void* bwc  = d_in[18];

  float* W      = (float*)d_ws;
  float* qT     = W;               // 131072 (QF hi/lo bf16 from k_pack)
  float* P      = W + 131072;      // 786432 (loop-dead after k_pp2; reused as pbuf)
  float* pp2    = W + 917504;      // 786432
  float* W1f    = W + 1703936;     // 262144
  float* W2f    = W + 1966080;     // 524288
  float* Wwcf   = W + 2490368;     // 524288
  float* WrmTf  = W + 3014656;     // 262144
  float* cbuf   = W + 3276800;     // 65536
  float* actb   = W + 3538944;     // 2 x 131072
  float* ubuf   = W + 3801088;     // 2 x 65536
  int*   flag   = (int*)(W + 3932160);
  float* ubase  = W + 3932224;     // 512
  float* mmb    = W + 3932736;     // 512
  float* mmc    = W + 3933248;     // 512
  float* pbuf   = P;               // 262144 used (8 chunks x 128 b x 256 n)
  float* kT     = W + 4194304;     // 12,845,056 (kmat transposed [b][n][d], fp32)
  float* GF     = W + 17039360;    // 524288 (Wrm@Wwc fused matrix, [e][i])

  hipLaunchKernelGGL(k_detect, dim3(1), dim3(256), 0, stream, (const u16*)ctx, flag);
  hipLaunchKernelGGL(k_prep1, dim3(1264), dim3(256), 0, stream,
                     Wcq, Wca, Wwc, Wrm, Wrc, Wra, bp, bcq, ctrl0, mem0, brm, bwc,
                     W1f, Wwcf, WrmTf, W2f, P, pp2, ubase, mmb, mmc, flag);
  hipLaunchKernelGGL(k_pack, dim3(1152), dim3(256), 0, stream,
                     q, (u16*)qT, kmat, kT, flag);
  hipLaunchKernelGGL(k_Pmfma, dim3(768), dim3(256), 0, stream, Wp, (const u16*)qT, P, flag);
  hipLaunchKernelGGL(k_gf, dim3(256), dim3(256), 0, stream, Wwcf, WrmTf, GF);
  hipLaunchKernelGGL(k_pp2,  dim3(768), dim3(512), 0, stream, P, Wcq, Wca, pp2, flag);
  hipLaunchKernelGGL(k_initB, dim3(64), dim3(256), 0, stream,
                     ubase, mem0, pp2, ubuf, actb, flag);

  for (int t = 0; t < TT; t++){
    int cur = t & 1, nxt = 1 - cur;
    float* act_cur  = actb + cur*131072;
    float* act_prev = actb + nxt*131072;   // [r_{t-1}; m_{t-2}] (r filled by KA)
    hipLaunchKernelGGL(k_KA, dim3(1088), dim3(512), 0, stream,
                       ctx, ubuf + cur*65536, pbuf, kT,
                       act_prev, cbuf, ubuf + nxt*65536,
                       pp2 + ((t+1 < TT) ? (t+1)*65536 : 0),
                       act_cur, bwc, t, flag);
    hipLaunchKernelGGL(k_KC, dim3(1280), dim3(512), 0, stream,
                       kmat, cbuf, act_prev, W2f, GF, mmc, mmb, Wwcf,
                       act_cur, pbuf, W1f, ubuf + nxt*65536, t, flag);
  }
  // epilogue: KA(t=TT): k-finish r_11 -> actb[1] rows 0..D; bwc preset -> actb[0] D..2D
  hipLaunchKernelGGL(k_KA, dim3(1088), dim3(512), 0, stream,
                     ctx, ubuf, pbuf, kT,
                     actb + 131072, cbuf, ubuf, pp2,
                     actb, bwc, TT, flag);
  hipLaunchKernelGGL(k_moutA, dim3(512), dim3(512), 0, stream,
                     actb + 131072, Wwcf, actb);
  hipLaunchKernelGGL(k_outT, dim3(64), dim3(256), 0, stream, actb, d_out, flag);
}

// Round 14
// 1008.379 us; speedup vs baseline: 1.3031x; 1.3031x over previous
//
#include <hip/hip_runtime.h>
#include <hip/hip_bf16.h>
#include <cstdint>

#define D  512
#define D2 1024
#define BB 128
#define SS 128
#define NN 196
#define TT 12

typedef unsigned short u16;
typedef __attribute__((ext_vector_type(8))) short short8v;
typedef __attribute__((ext_vector_type(4))) float f32x4;

__device__ __forceinline__ float bf2f(u16 h){
  union { unsigned int u; float f; } v; v.u = ((unsigned int)h) << 16; return v.f;
}

__device__ __forceinline__ float LDX(const void* p, size_t i, int isbf){
  if (isbf) return bf2f(((const u16*)p)[i]);
  return ((const float*)p)[i];
}

__device__ __forceinline__ float4 LD4(const void* p, size_t i, int isbf){
  if (isbf){
    ushort4 w = *(const ushort4*)((const u16*)p + i);
    return make_float4(bf2f(w.x), bf2f(w.y), bf2f(w.z), bf2f(w.w));
  }
  return *(const float4*)((const float*)p + i);
}

// split fp32 into bf16 hi (truncation) + bf16 lo (truncated residual).
__device__ __forceinline__ void bfsplit(float x, short &h, short &l){
  unsigned u = __float_as_uint(x);
  unsigned hu = u & 0xFFFF0000u;
  float r = x - __uint_as_float(hu);
  h = (short)(u >> 16);
  l = (short)(__float_as_uint(r) >> 16);
}

// ---------------- detect input dtype ----------------
__global__ __launch_bounds__(256) void k_detect(const u16* ctx, int* flag){
  __shared__ int cnt;
  if (threadIdx.x == 0) cnt = 0;
  __syncthreads();
  int bad = 0;
  for (int i = threadIdx.x; i < 8192; i += 256){
    int e = (ctx[i] >> 7) & 0xFF;
    if (e == 0xFF || (e != 0 && (e < 90 || e > 160))) bad++;
  }
  atomicAdd(&cnt, bad);
  __syncthreads();
  if (threadIdx.x == 0) *flag = (cnt > 100) ? 0 : 1;   // 1 = bf16, 0 = fp32
}

// ---------------- prep1: weight transposes + P/pp2 presets + initA ----------------
__global__ __launch_bounds__(256) void k_prep1(const void* Wcq, const void* Wca,
      const void* Wwc, const void* Wrm, const void* Wrc, const void* Wra,
      const void* bp, const void* bcq, const void* ctrl0, const void* mem0, const void* brm,
      float* W1f, float* Wwcf, float* WrmTf, float* W2f,
      float* P, float* pp2, float* ubase, float* mmb, const int* flag){
  const int isbf = *flag;
  __shared__ float lds[32][33];
  int bk = blockIdx.x, tid = threadIdx.x;
  int tx = tid & 31, ty = tid >> 5;
  if (bk >= 1216){                       // initA: 32 blocks
    int ib = bk - 1216;
    int lane = tid & 63, w = tid >> 6;
    int grp = lane >> 3, k = lane & 7;
    int isU = (ib < 16);
    int o = (isU ? ib : ib - 16)*32 + w*8 + grp;
    const void* vec = isU ? ctrl0 : mem0;
    const void* mat = isU ? Wcq : Wrm;
    int ld = isU ? D2 : D;
    float acc = 0.f;
    #pragma unroll 4
    for (int it = 0; it < 16; it++){
      int d = it*32 + k*4;
      float4 v = LD4(vec, d, isbf);
      float4 m = LD4(mat, (size_t)o*ld + d, isbf);
      acc += v.x*m.x + v.y*m.y + v.z*m.z + v.w*m.w;
    }
    acc += __shfl_xor(acc, 1, 64);
    acc += __shfl_xor(acc, 2, 64);
    acc += __shfl_xor(acc, 4, 64);
    if (k == 0){
      if (isU) ubase[o] = acc * LDX(Wca, o, isbf);
      else     mmb[o]   = acc + LDX(brm, o, isbf);
    }
    return;
  }
  if (bk >= 1152){                       // pp2 preset = bcq[j]*Wca[j] : 64 blocks
    int l = bk - 1152;
    for (int idx = l*256 + tid; idx < 786432; idx += 64*256){
      int j = (idx >> 7) & 511;
      pp2[idx] = LDX(bcq, j, isbf) * LDX(Wca, j, isbf);
    }
    return;
  }
  if (bk >= 1088){                       // P preset = bp : 64 blocks
    int l = bk - 1088;
    for (int idx = l*256 + tid; idx < 786432; idx += 64*256)
      P[idx] = LDX(bp, idx >> 7, isbf);
    return;
  }
  if (bk >= 1024){                       // W2f = Wrc * Wra : 64 blocks
    int l = bk - 1024;
    if (isbf){
      const u16* w = (const u16*)Wrc; const u16* s = (const u16*)Wra;
      for (int idx = l*256 + tid; idx < 524288; idx += 64*256)
        W2f[idx] = bf2f(w[idx]) * bf2f(s[idx >> 10]);
    } else {
      const float* w = (const float*)Wrc; const float* s = (const float*)Wra;
      for (int idx = l*256 + tid; idx < 524288; idx += 64*256)
        W2f[idx] = w[idx] * s[idx >> 10];
    }
    return;
  }
  const void* in = nullptr; const void* scale = nullptr; float* out = nullptr;
  int ld = 0, R = 0, tR = 0, tC = 0;
  if (bk < 256)      { int l = bk;       in = Wcq; ld = 1024; R = 512; out = W1f;  scale = Wca; tR = l & 15; tC = l >> 4; }
  else if (bk < 768) { int l = bk - 256; in = Wwc; ld = 1024; R = 512; out = Wwcf; tR = l & 15; tC = l >> 4; }
  else               { int l = bk - 768; in = Wrm; ld = 512;  R = 512; out = WrmTf;tR = l & 15; tC = l >> 4; }
  int r0 = tR*32, c0 = tC*32;
  #pragma unroll
  for (int kk = 0; kk < 4; kk++){
    int r = r0 + ty + kk*8;
    float v = LDX(in, (size_t)r*ld + c0 + tx, isbf);
    if (scale) v *= LDX(scale, r, isbf);
    lds[tx][ty + kk*8] = v;
  }
  __syncthreads();
  #pragma unroll
  for (int kk = 0; kk < 4; kk++){
    int oc = ty + kk*8;
    out[(size_t)(c0 + oc)*R + r0 + tx] = lds[oc][tx];
  }
}

// ---------------- k_pack: [bk<128] q->QF hi/lo bf16 ; [bk>=128] kmat -> kT (wide transpose) --
__global__ __launch_bounds__(256) void k_pack(const void* q, u16* QF,
                                              const void* kmat, float* kT, const int* flag){
  const int isbf = *flag;
  __shared__ float lds[64][201];
  int bk = blockIdx.x, tid = threadIdx.x;
  if (bk < 128){
    u16* QH = QF;
    u16* QL = QF + 131072;
    for (int idx = bk*256 + tid; idx < 131072; idx += 128*256){
      int b = idx >> 10, x = idx & 1023;
      int o = ((x >> 3) << 10) + (b << 3) + (x & 7);
      if (isbf){
        QH[o] = ((const u16*)q)[idx];
        QL[o] = 0;
      } else {
        short h, l;
        bfsplit(((const float*)q)[idx], h, l);
        QH[o] = (u16)h;
        QL[o] = (u16)l;
      }
    }
    return;
  }
  int l = bk - 128;                 // 1024 = 128 b x 8 d-tiles(64)
  int b = l >> 3, dt = l & 7;
  int d0 = dt*64;
  int r = tid >> 2, q4 = tid & 3;
  const size_t rowbase = ((size_t)b*D + d0 + r)*NN;
  #pragma unroll
  for (int p = 0; p < 13; p++){
    int j = q4 + p*4;
    if (j < 49){
      float4 v = LD4(kmat, rowbase + 4*j, isbf);
      *(float4*)&lds[r][4*j] = v;
    }
  }
  __syncthreads();
  int n_loc = tid >> 4, f = tid & 15;
  #pragma unroll
  for (int p = 0; p < 13; p++){
    int n = p*16 + n_loc;
    if (n < NN){
      float4 v = make_float4(lds[4*f][n], lds[4*f+1][n], lds[4*f+2][n], lds[4*f+3][n]);
      *(float4*)&kT[((size_t)b*NN + n)*D + d0 + 4*f] = v;
    }
  }
}

// ---------------- k_Pmfma: P += Wp @ qT via 16x16x32 bf16 MFMA (split hi/lo) ----------------
__global__ __launch_bounds__(256) void k_Pmfma(const void* Wp, const u16* QF,
                                               float* P, const int* flag){
  const int isbf = *flag;
  const u16* QH = QF;
  const u16* QL = QF + 131072;
  int bk = blockIdx.x;
  int mt = bk >> 2, kc = bk & 3;
  int m0 = mt * 32;
  int tid = threadIdx.x;
  int ln = tid & 63, w = tid >> 6;
  int msub = w >> 1, nh = w & 1;
  int row  = m0 + msub*16 + (ln & 15);   // A row (0..6143)
  int koff = ln >> 4;                    // 0..3 : k-subgroup of 8
  f32x4 acc[4];
  #pragma unroll
  for (int i = 0; i < 4; i++) acc[i] = (f32x4){0.f, 0.f, 0.f, 0.f};

  for (int ks = 0; ks < 8; ks++){
    int k0 = kc*256 + ks*32;
    short8v ah, al;
    if (isbf){
      const u16* wr = (const u16*)Wp + (size_t)row*D2 + k0 + koff*8;
      ah = *(const short8v*)wr;
    } else {
      const float* wr = (const float*)Wp + (size_t)row*D2 + k0 + koff*8;
      float4 f0 = *(const float4*)wr;
      float4 f1 = *(const float4*)(wr + 4);
      float fs[8] = {f0.x, f0.y, f0.z, f0.w, f1.x, f1.y, f1.z, f1.w};
      #pragma unroll
      for (int j = 0; j < 8; j++){
        short h, l;
        bfsplit(fs[j], h, l);
        ah[j] = h; al[j] = l;
      }
    }
    int qrow = ((k0 >> 3) + koff) << 10;   // *1024
    #pragma unroll
    for (int nt = 0; nt < 4; nt++){
      int col = (nh*4 + nt)*16 + (ln & 15);
      short8v bh = *(const short8v*)(QH + qrow + (col << 3));
      acc[nt] = __builtin_amdgcn_mfma_f32_16x16x32_bf16(ah, bh, acc[nt], 0, 0, 0);
      if (!isbf){
        short8v bl = *(const short8v*)(QL + qrow + (col << 3));
        acc[nt] = __builtin_amdgcn_mfma_f32_16x16x32_bf16(ah, bl, acc[nt], 0, 0, 0);
        acc[nt] = __builtin_amdgcn_mfma_f32_16x16x32_bf16(al, bh, acc[nt], 0, 0, 0);
      }
    }
  }
  // C/D layout (m89-verified): col = lane&15, row = (lane>>4)*4 + reg
  int orow = m0 + msub*16 + (ln >> 4)*4;
  #pragma unroll
  for (int nt = 0; nt < 4; nt++){
    int b = (nh*4 + nt)*16 + (ln & 15);
    #pragma unroll
    for (int r = 0; r < 4; r++)
      atomicAdd(&P[(size_t)(orow + r)*BB + b], acc[nt][r]);
  }
}

// ---------------- K_pp2: K-split x2, atomic into (bcq*Wca)-preset pp2 ----------------
__global__ __launch_bounds__(512) void k_pp2(const float* P, const void* Wcq,
                                             const void* Wca, float* pp2, const int* flag){
  const int isbf = *flag;
  int bk = blockIdx.x;                      // 768 = 12t * 32jt * 2kc
  int t = bk >> 6; int r = bk & 63; int jt = r >> 1; int kc = r & 1;
  int tid = threadIdx.x;
  int b = tid & 127;
  int ih = __builtin_amdgcn_readfirstlane(tid >> 7);
  int j0 = jt*16 + ih*4;
  float acc[4] = {0.f, 0.f, 0.f, 0.f};
  int e0k = kc*256;
  if (isbf){
    const u16* w = (const u16*)Wcq;
    for (int e = e0k; e < e0k + 256; e += 8){
      float a[8];
      #pragma unroll
      for (int u = 0; u < 8; u++) a[u] = P[(size_t)(t*D + e + u)*BB + b];
      #pragma unroll
      for (int kk = 0; kk < 4; kk++){
        ushort4 w0 = *(const ushort4*)(w + (size_t)(j0+kk)*D2 + D + e);
        ushort4 w1 = *(const ushort4*)(w + (size_t)(j0+kk)*D2 + D + e + 4);
        acc[kk] += a[0]*bf2f(w0.x) + a[1]*bf2f(w0.y) + a[2]*bf2f(w0.z) + a[3]*bf2f(w0.w)
                 + a[4]*bf2f(w1.x) + a[5]*bf2f(w1.y) + a[6]*bf2f(w1.z) + a[7]*bf2f(w1.w);
      }
    }
  } else {
    const float* w = (const float*)Wcq;
    for (int e = e0k; e < e0k + 256; e += 8){
      float a[8];
      #pragma unroll
      for (int u = 0; u < 8; u++) a[u] = P[(size_t)(t*D + e + u)*BB + b];
      #pragma unroll
      for (int kk = 0; kk < 4; kk++){
        float4 w0 = *(const float4*)(w + (size_t)(j0+kk)*D2 + D + e);
        float4 w1 = *(const float4*)(w + (size_t)(j0+kk)*D2 + D + e + 4);
        acc[kk] += a[0]*w0.x + a[1]*w0.y + a[2]*w0.z + a[3]*w0.w
                 + a[4]*w1.x + a[5]*w1.y + a[6]*w1.z + a[7]*w1.w;
      }
    }
  }
  #pragma unroll
  for (int kk = 0; kk < 4; kk++)
    atomicAdd(&pp2[(size_t)(t*D + j0 + kk)*BB + b], acc[kk] * LDX(Wca, j0 + kk, isbf));
}

// ---------------- K_initB: u0 and m_{-1} (mm handled in-kernel now) ----------------
__global__ __launch_bounds__(256) void k_initB(const float* ubase, const void* mem0,
                                               const float* pp2,
                                               float* u0, float* act0, const int* flag){
  const int isbf = *flag;
  for (int idx = blockIdx.x*256 + threadIdx.x; idx < 2*D*BB; idx += 64*256){
    if (idx < D*BB) u0[idx] = ubase[idx >> 7] + pp2[idx];
    else          { int x = idx - D*BB; act0[D*BB + x] = LDX(mem0, x >> 7, isbf); }
  }
}

// ================ K1: [k-attn finish of t-1 -> r_{t-1}] + [ctx logits of t] ========
// bk <  512 : (b, qc) finish: pbuf partials -> softmax -> weighted sum from kT  (t>0)
// bk < 1024 : (b, sc) ctx logits: gbuf[b][s] = dot(u_cur[:,b], ctx[b,s,:])      (t<TT)
__global__ __launch_bounds__(512) void k_K1(const void* ctx, const float* u_cur,
                                            float* gbuf, const float* pbuf, const float* kT,
                                            float* r_out, int t, const int* flag){
  __shared__ float sm[1024];
  int bk = blockIdx.x, tid = threadIdx.x;
  const int isbf = *flag;
  if (bk < 512){
    if (t == 0) return;
    float* lg   = sm;            // 256
    float* red  = sm + 256;      // 256
    float* psum = sm + 512;      // 512
    int b = bk & 127, qc = bk >> 7;
    if (tid < 256){
      float s;
      if (tid < NN){
        s = 0.f;
        #pragma unroll
        for (int c = 0; c < 8; c++)
          s += pbuf[((size_t)c*BB + b)*256 + tid];
      } else s = -INFINITY;
      lg[tid] = s; red[tid] = s;
    }
    __syncthreads();
    for (int off = 128; off; off >>= 1){ if (tid < off) red[tid] = fmaxf(red[tid], red[tid+off]); __syncthreads(); }
    float M = red[0];
    __syncthreads();
    if (tid < 256){ float e = (tid < NN) ? __expf(lg[tid] - M) : 0.f; lg[tid] = e; red[tid] = e; }
    __syncthreads();
    for (int off = 128; off; off >>= 1){ if (tid < off) red[tid] += red[tid+off]; __syncthreads(); }
    float inv = 1.f / red[0];
    int ng = tid >> 7, dl = tid & 127;     // 4 n-groups x 128 d-lanes
    const float* kTb = kT + ((size_t)b*NN + ng*49)*D + qc*128 + dl;
    float acc = 0.f;
    for (int j = 0; j < 49; j++)
      acc += lg[ng*49 + j] * kTb[(size_t)j*D];
    psum[ng*128 + dl] = acc;
    __syncthreads();
    if (tid < 128)
      r_out[(size_t)(qc*128 + tid)*BB + b] =
        (psum[tid] + psum[128 + tid] + psum[256 + tid] + psum[384 + tid]) * inv;
    return;
  }
  // ---- ctx logits ----
  if (t >= TT) return;
  int l = bk - 512;
  int b = l & 127, sc = l >> 7;
  float* us = sm;                // 512
  us[tid] = u_cur[(size_t)tid*BB + b];
  __syncthreads();
  int lane = tid & 63, wv = tid >> 6;
  float ur[8];
  #pragma unroll
  for (int j = 0; j < 8; j++) ur[j] = us[lane*8 + j];
  #pragma unroll
  for (int rr = 0; rr < 4; rr++){
    int s = sc*32 + wv*4 + rr;
    size_t base = ((size_t)(b*SS + s))*D + lane*8;
    float4 c0 = LD4(ctx, base, isbf);
    float4 c1 = LD4(ctx, base + 4, isbf);
    float dot = ur[0]*c0.x + ur[1]*c0.y + ur[2]*c0.z + ur[3]*c0.w
              + ur[4]*c1.x + ur[5]*c1.y + ur[6]*c1.z + ur[7]*c1.w;
    #pragma unroll
    for (int off = 32; off; off >>= 1) dot += __shfl_down(dot, off, 64);
    if (lane == 0) gbuf[b*SS + s] = dot;
  }
}

// ================ K2: [ctx finish -> cbuf] + [m-gemv] + housekeeping ================
// bk < 512         : (b, qc) softmax over 128 logits + weighted sum over s -> cbuf
// bk in [512,1024) : m-gemv: act_cur rows D..2D += Wwcf^T · act_prev (bwc preset; t>0)
// bk in [1024,1056): u_nxt preset = pp2_next (t<TT-1)
__global__ __launch_bounds__(512) void k_K2(const void* ctx, const float* gbuf, float* cbuf,
                                            const float* act_prev, float* act_cur,
                                            float* u_nxt, const float* pp2_next,
                                            const float* Wwcf, int t, const int* flag){
  __shared__ float sm[768];
  int bk = blockIdx.x, tid = threadIdx.x;
  const int isbf = *flag;
  if (bk < 512){
    float* lg   = sm;            // 128
    float* red  = sm + 128;      // 128
    float* psum = sm + 256;      // 512
    int b = bk & 127, qc = bk >> 7;
    if (tid < 128){ float v = gbuf[b*SS + tid]; lg[tid] = v; red[tid] = v; }
    __syncthreads();
    for (int off = 64; off; off >>= 1){ if (tid < off) red[tid] = fmaxf(red[tid], red[tid+off]); __syncthreads(); }
    float M = red[0];
    __syncthreads();
    if (tid < 128){ float e = __expf(lg[tid] - M); lg[tid] = e; red[tid] = e; }
    __syncthreads();
    for (int off = 64; off; off >>= 1){ if (tid < off) red[tid] += red[tid+off]; __syncthreads(); }
    float inv = 1.f / red[0];
    int sg = tid >> 7, dl = tid & 127;     // 4 s-groups x 128 d-lanes
    int d = qc*128 + dl;
    float acc = 0.f;
    for (int j = 0; j < 32; j++){
      int s = sg*32 + j;
      acc += lg[s] * LDX(ctx, ((size_t)(b*SS + s))*D + d, isbf);
    }
    psum[sg*128 + dl] = acc;
    __syncthreads();
    if (tid < 128)
      cbuf[(size_t)(qc*128 + tid)*BB + b] =
        (psum[tid] + psum[128 + tid] + psum[256 + tid] + psum[384 + tid]) * inv;
    return;
  }
  int b = tid & 127;
  int ih = __builtin_amdgcn_readfirstlane(tid >> 7);   // 0..3
  if (bk < 1024){
    if (t == 0) return;
    int l = bk - 512;                    // 0..511
    int it = l >> 3, kc = l & 7;
    int ih0 = ih & 1, ih1 = ih >> 1;
    int i0 = it*8 + ih0*4;
    int e0 = kc*128 + ih1*64;
    float acc[4] = {0.f,0.f,0.f,0.f};
    for (int e = e0; e < e0 + 64; e += 8){
      float av[8];
      #pragma unroll
      for (int u = 0; u < 8; u++) av[u] = act_prev[(size_t)(e+u)*BB + b];
      #pragma unroll
      for (int u = 0; u < 8; u++){
        float4 w0 = *(const float4*)(Wwcf + (size_t)(e+u)*D + i0);
        acc[0]+=av[u]*w0.x; acc[1]+=av[u]*w0.y; acc[2]+=av[u]*w0.z; acc[3]+=av[u]*w0.w;
      }
    }
    #pragma unroll
    for (int kk = 0; kk < 4; kk++)
      atomicAdd(&act_cur[(size_t)(D + i0 + kk)*BB + b], acc[kk]);
  } else {
    if (t >= TT-1) return;
    int l = bk - 1024;
    for (int x = l*512 + tid; x < D*BB; x += 32*512) u_nxt[x] = pp2_next[x];
  }
}

// ================ KC1: fused [w,mm,u2 in-block] + k-attn logit partials + u-gemv + preset ===
__global__ __launch_bounds__(512) void k_KC1(const void* kmat, const float* cbuf,
                                             const float* act_cur, const float* W2f,
                                             const float* WrmTf, const void* brm,
                                             const float* mmb, float* pbuf,
                                             const float* W1f, float* u_nxt,
                                             float* act_nxt, const void* bwc,
                                             int t, const int* flag){
  __shared__ float cb[512];
  __shared__ float mv[512];
  __shared__ float wv2[256];
  __shared__ float mmv[128];
  __shared__ float u2[128];
  int bk = blockIdx.x, tid = threadIdx.x;
  const int isbf = *flag;
  if (bk < 512){
    int b = bk & 127, ch2 = bk >> 7;      // ch2: 0..3
    int d0 = ch2*128;
    cb[tid] = cbuf[(size_t)tid*BB + b];
    if (t > 0) mv[tid] = act_cur[(size_t)(D + tid)*BB + b];
    __syncthreads();
    if (tid < 256){
      int e = (tid < 128) ? (d0 + tid) : (D + d0 + (tid - 128));
      float c0=0.f,c1=0.f,c2=0.f,c3=0.f,c4=0.f,c5=0.f,c6=0.f,c7=0.f;
      for (int j = 0; j < 512; j += 8){
        c0 += cb[j  ]*W2f[(size_t)(j  )*D2 + e];
        c1 += cb[j+1]*W2f[(size_t)(j+1)*D2 + e];
        c2 += cb[j+2]*W2f[(size_t)(j+2)*D2 + e];
        c3 += cb[j+3]*W2f[(size_t)(j+3)*D2 + e];
        c4 += cb[j+4]*W2f[(size_t)(j+4)*D2 + e];
        c5 += cb[j+5]*W2f[(size_t)(j+5)*D2 + e];
        c6 += cb[j+6]*W2f[(size_t)(j+6)*D2 + e];
        c7 += cb[j+7]*W2f[(size_t)(j+7)*D2 + e];
      }
      wv2[tid] = (((c0+c1)+(c2+c3)) + ((c4+c5)+(c6+c7)));
    } else if (tid < 384){
      int tm = tid - 256;
      int d = d0 + tm;
      if (t == 0){
        mmv[tm] = mmb[d];
      } else {
        float c0=0.f,c1=0.f,c2=0.f,c3=0.f,c4=0.f,c5=0.f,c6=0.f,c7=0.f;
        for (int j = 0; j < 512; j += 8){
          c0 += mv[j  ]*WrmTf[(size_t)(j  )*D + d];
          c1 += mv[j+1]*WrmTf[(size_t)(j+1)*D + d];
          c2 += mv[j+2]*WrmTf[(size_t)(j+2)*D + d];
          c3 += mv[j+3]*WrmTf[(size_t)(j+3)*D + d];
          c4 += mv[j+4]*WrmTf[(size_t)(j+4)*D + d];
          c5 += mv[j+5]*WrmTf[(size_t)(j+5)*D + d];
          c6 += mv[j+6]*WrmTf[(size_t)(j+6)*D + d];
          c7 += mv[j+7]*WrmTf[(size_t)(j+7)*D + d];
        }
        mmv[tm] = LDX(brm, d, isbf) + (((c0+c1)+(c2+c3)) + ((c4+c5)+(c6+c7)));
      }
    }
    __syncthreads();
    if (tid < 128) u2[tid] = wv2[tid]*mmv[tid] + wv2[128 + tid];
    __syncthreads();
    int half = tid >> 8;                  // 0..1 -> 64-d sub-chunk
    int n = tid & 255;
    int dd0 = half*64;
    float part = 0.f;
    if (n < NN){
      float c[8];
      #pragma unroll
      for (int u = 0; u < 8; u++) c[u] = 0.f;
      if (isbf){
        const u16* kb = (const u16*)kmat + (size_t)b*D*NN + (size_t)(d0+dd0)*NN + n;
        for (int dd = 0; dd < 64; dd += 8){
          #pragma unroll
          for (int u = 0; u < 8; u++) c[u] += u2[dd0+dd+u]*bf2f(kb[(size_t)(dd+u)*NN]);
        }
      } else {
        const float* kb = (const float*)kmat + (size_t)b*D*NN + (size_t)(d0+dd0)*NN + n;
        for (int dd = 0; dd < 64; dd += 8){
          #pragma unroll
          for (int u = 0; u < 8; u++) c[u] += u2[dd0+dd+u]*kb[(size_t)(dd+u)*NN];
        }
      }
      part = (((c[0]+c[1]) + (c[2]+c[3])) + ((c[4]+c[5]) + (c[6]+c[7])));
    }
    int chunk = ch2*2 + half;             // 0..7
    pbuf[((size_t)chunk*BB + b)*256 + n] = part;
    return;
  }
  int b = tid & 127;
  int ih = __builtin_amdgcn_readfirstlane(tid >> 7);   // 0..3
  if (bk < 768){
    if (t >= TT-1) return;
    int l = bk - 512;                    // 0..255
    int jt = l >> 1, kc = l & 1;
    int j = jt*4 + ih;
    float c0 = 0.f, c1 = 0.f, c2 = 0.f, c3 = 0.f, c4 = 0.f, c5 = 0.f, c6 = 0.f, c7 = 0.f;
    int e0 = kc*256;
    for (int e = e0; e < e0 + 256; e += 8){
      c0 += cbuf[(e  )*BB + b] * W1f[(size_t)(e  )*D + j];
      c1 += cbuf[(e+1)*BB + b] * W1f[(size_t)(e+1)*D + j];
      c2 += cbuf[(e+2)*BB + b] * W1f[(size_t)(e+2)*D + j];
      c3 += cbuf[(e+3)*BB + b] * W1f[(size_t)(e+3)*D + j];
      c4 += cbuf[(e+4)*BB + b] * W1f[(size_t)(e+4)*D + j];
      c5 += cbuf[(e+5)*BB + b] * W1f[(size_t)(e+5)*D + j];
      c6 += cbuf[(e+6)*BB + b] * W1f[(size_t)(e+6)*D + j];
      c7 += cbuf[(e+7)*BB + b] * W1f[(size_t)(e+7)*D + j];
    }
    float acc = (((c0+c1)+(c2+c3)) + ((c4+c5)+(c6+c7)));
    atomicAdd(&u_nxt[(size_t)j*BB + b], acc);
  } else {
    // bwc preset into act_nxt rows D..2D — runs EVERY step incl. t=11
    int l = bk - 768;
    for (int x = l*512 + tid; x < D*BB; x += 32*512)
      act_nxt[D*BB + x] = LDX(bwc, x >> 7, isbf);
  }
}

// ================ k_moutA: m_T = bwc + Wwc^T [r_T; m_{T-1}] (K-split x16) ================
__global__ __launch_bounds__(512) void k_moutA(const float* act_fin, const float* Wwcf,
                                               float* act_out){
  int bk = blockIdx.x, tid = threadIdx.x;   // 512 blocks
  int b = tid & 127;
  int ih = __builtin_amdgcn_readfirstlane(tid >> 7);
  int it = bk >> 3, kc = bk & 7;
  int ih0 = ih & 1, ih1 = ih >> 1;
  int i0 = it*8 + ih0*4;
  int e0 = kc*128 + ih1*64;
  float acc[4] = {0.f,0.f,0.f,0.f};
  for (int e = e0; e < e0 + 64; e += 8){
    float av[8];
    #pragma unroll
    for (int u = 0; u < 8; u++) av[u] = act_fin[(size_t)(e+u)*BB + b];
    #pragma unroll
    for (int u = 0; u < 8; u++){
      float4 w0 = *(const float4*)(Wwcf + (size_t)(e+u)*D + i0);
      acc[0]+=av[u]*w0.x; acc[1]+=av[u]*w0.y; acc[2]+=av[u]*w0.z; acc[3]+=av[u]*w0.w;
    }
  }
  #pragma unroll
  for (int kk = 0; kk < 4; kk++)
    atomicAdd(&act_out[(size_t)(D + i0 + kk)*BB + b], acc[kk]);
}

// ================ k_outT: m[i,b] fp32 -> out[b,i] (bf16 or f32) ================
__global__ __launch_bounds__(256) void k_outT(const float* act_fin, void* out, const int* flag){
  const int isbf = *flag;
  __shared__ float lds[32][33];
  int bk = blockIdx.x;
  int it = bk >> 2, bt = bk & 3;
  int tx = threadIdx.x & 31, ty = threadIdx.x >> 5;
  #pragma unroll
  for (int kk = 0; kk < 4; kk++){
    int i = it*32 + ty + kk*8;
    lds[tx][ty + kk*8] = act_fin[(size_t)(D + i)*BB + bt*32 + tx];
  }
  __syncthreads();
  if (isbf){
    __hip_bfloat16* o = (__hip_bfloat16*)out;
    #pragma unroll
    for (int kk = 0; kk < 4; kk++){
      int bb = bt*32 + ty + kk*8;
      o[(size_t)bb*D + it*32 + tx] = __float2bfloat16(lds[ty + kk*8][tx]);
    }
  } else {
    float* o = (float*)out;
    #pragma unroll
    for (int kk = 0; kk < 4; kk++){
      int bb = bt*32 + ty + kk*8;
      o[(size_t)bb*D + it*32 + tx] = lds[ty + kk*8][tx];
    }
  }
}

extern "C" void kernel_launch(void* const* d_in, const int* in_sizes, int n_in,
                              void* d_out, int out_size, void* d_ws, size_t ws_size,
                              hipStream_t stream){
  const void* ctx  = d_in[0];
  const void* q    = d_in[1];
  const void* kmat = d_in[2];
  const void* mem0 = d_in[3];
  const void* ctrl0= d_in[4];
  const void* Wp   = d_in[5];
  const void* bp   = d_in[6];
  const void* Wcq  = d_in[7];
  const void* bcq  = d_in[8];
  const void* Wca  = d_in[9];
  const void* Wrm  = d_in[11];
  const void* brm  = d_in[12];
  const void* Wrc  = d_in[13];
  const void* Wra  = d_in[15];
  const void* Wwc  = d_in[17];
  const void* bwc  = d_in[18];

  float* W      = (float*)d_ws;
  float* qT     = W;               // 131072 (QF hi/lo bf16 from k_pack)
  float* P      = W + 131072;      // 786432 (loop-dead after k_pp2; reused as pbuf)
  float* pp2    = W + 917504;      // 786432
  float* W1f    = W + 1703936;     // 262144
  float* W2f    = W + 1966080;     // 524288
  float* Wwcf   = W + 2490368;     // 524288
  float* WrmTf  = W + 3014656;     // 262144
  float* cbuf   = W + 3276800;     // 65536
  float* actb   = W + 3538944;     // 2 x 131072
  float* ubuf   = W + 3801088;     // 2 x 65536
  int*   flag   = (int*)(W + 3932160);
  float* ubase  = W + 3932224;     // 512
  float* mmb    = W + 3932736;     // 512
  float* gbuf   = W + 3933248;     // 16384 (ctx-attn logits)
  float* pbuf   = P;               // 262144 used (8 chunks x 128 b x 256 n)
  float* kT     = W + 4194304;     // 12,845,056 (kmat transposed [b][n][d], fp32)

  hipLaunchKernelGGL(k_detect, dim3(1), dim3(256), 0, stream, (const u16*)ctx, flag);
  hipLaunchKernelGGL(k_prep1, dim3(1248), dim3(256), 0, stream,
                     Wcq, Wca, Wwc, Wrm, Wrc, Wra, bp, bcq, ctrl0, mem0, brm,
                     W1f, Wwcf, WrmTf, W2f, P, pp2, ubase, mmb, flag);
  hipLaunchKernelGGL(k_pack, dim3(1152), dim3(256), 0, stream,
                     q, (u16*)qT, kmat, kT, flag);
  hipLaunchKernelGGL(k_Pmfma, dim3(768), dim3(256), 0, stream, Wp, (const u16*)qT, P, flag);
  hipLaunchKernelGGL(k_pp2,  dim3(768), dim3(512), 0, stream, P, Wcq, Wca, pp2, flag);
  hipLaunchKernelGGL(k_initB, dim3(64), dim3(256), 0, stream,
                     ubase, mem0, pp2, ubuf, actb, flag);

  for (int t = 0; t < TT; t++){
    int cur = t & 1, nxt = 1 - cur;
    float* act_cur  = actb + cur*131072;
    float* act_prev = actb + nxt*131072;   // [r_{t-1}; m_{t-2}] (r filled by K1)
    hipLaunchKernelGGL(k_K1, dim3(1024), dim3(512), 0, stream,
                       ctx, ubuf + cur*65536, gbuf, pbuf, kT,
                       act_prev, t, flag);
    hipLaunchKernelGGL(k_K2, dim3(1056), dim3(512), 0, stream,
                       ctx, gbuf, cbuf, act_prev, act_cur,
                       ubuf + nxt*65536,
                       pp2 + ((t+1 < TT) ? (t+1)*65536 : 0), Wwcf, t, flag);
    hipLaunchKernelGGL(k_KC1, dim3(800), dim3(512), 0, stream,
                       kmat, cbuf, act_cur, W2f, WrmTf, brm, mmb, pbuf,
                       W1f, ubuf + nxt*65536,
                       actb + nxt*131072, bwc, t, flag);
  }
  // epilogue: finish r_11 into actb[1] rows 0..D (K1 with t=TT: only finish blocks run)
  hipLaunchKernelGGL(k_K1, dim3(512), dim3(512), 0, stream,
                     ctx, ubuf, gbuf, pbuf, kT,
                     actb + 131072, TT, flag);
  hipLaunchKernelGGL(k_moutA, dim3(512), dim3(512), 0, stream,
                     actb + 131072, Wwcf, actb);
  hipLaunchKernelGGL(k_outT, dim3(64), dim3(256), 0, stream, actb, d_out, flag);
}